// Round 1
// baseline (1073.168 us; speedup 1.0000x reference)
//
#include <hip/hip_runtime.h>
#include <math.h>

#define B_ 32
#define N_ 8192
#define G_ 128
#define K_ 32
#define H_ 128
#define D_ 384

#define TOK_OFF 0
#define CEN_OFF (B_ * G_ * D_)                    // 1572864
#define GIDX_OFF (B_ * G_ * D_ + B_ * G_ * 3)     // 1585152

// ---------------- wave-level argmax/argmin carrying payload ----------------

__device__ __forceinline__ void waveArgMaxC(float& v, int& i, float& x, float& y, float& z) {
#pragma unroll
    for (int off = 32; off >= 1; off >>= 1) {
        float ov = __shfl_xor(v, off);
        int   oi = __shfl_xor(i, off);
        float ox = __shfl_xor(x, off);
        float oy = __shfl_xor(y, off);
        float oz = __shfl_xor(z, off);
        if (ov > v || (ov == v && oi < i)) { v = ov; i = oi; x = ox; y = oy; z = oz; }
    }
}

__device__ __forceinline__ void waveArgMinF(float& v, int& i) {
#pragma unroll
    for (int off = 32; off >= 1; off >>= 1) {
        float ov = __shfl_xor(v, off);
        int   oi = __shfl_xor(i, off);
        if (ov < v || (ov == v && oi < i)) { v = ov; i = oi; }
    }
}

// ---------------- Kernel 1: farthest point sampling ----------------
// One block per batch. 1024 threads, 8 points each, all in registers.
// Argmax reduction carries the winning point's coords (no xyz LDS staging).

__global__ __launch_bounds__(1024) void fps_kernel(
    const float* __restrict__ xyz,
    float* __restrict__ centers_out,   // d_out + CEN_OFF
    int* __restrict__ cidx)            // workspace (B*G ints)
{
    __shared__ double sred[3][16];
    __shared__ float  rv[16], rx[16], ry[16], rz[16];
    __shared__ int    ri[16];
    __shared__ float  bmx, bmy, bmz;          // mean broadcast
    __shared__ float  bcv, bcx, bcy, bcz;     // argmax broadcast
    __shared__ int    bci;

    const int b    = blockIdx.x;
    const int tid  = threadIdx.x;
    const int lane = tid & 63;
    const int wid  = tid >> 6;
    const float* base = xyz + (size_t)b * N_ * 3;

    float lx[8], ly[8], lz[8];
    double sx = 0.0, sy = 0.0, sz = 0.0;
#pragma unroll
    for (int r = 0; r < 8; ++r) {
        const int i = tid + r * 1024;
        const float X = base[i * 3 + 0];
        const float Y = base[i * 3 + 1];
        const float Z = base[i * 3 + 2];
        lx[r] = X; ly[r] = Y; lz[r] = Z;
        sx += X; sy += Y; sz += Z;
    }
    // block mean (double accumulation)
#pragma unroll
    for (int off = 32; off >= 1; off >>= 1) {
        sx += __shfl_xor(sx, off);
        sy += __shfl_xor(sy, off);
        sz += __shfl_xor(sz, off);
    }
    if (lane == 0) { sred[0][wid] = sx; sred[1][wid] = sy; sred[2][wid] = sz; }
    __syncthreads();
    if (tid == 0) {
        double tx = 0, ty = 0, tz = 0;
        for (int w = 0; w < 16; ++w) { tx += sred[0][w]; ty += sred[1][w]; tz += sred[2][w]; }
        bmx = (float)(tx / (double)N_);
        bmy = (float)(ty / (double)N_);
        bmz = (float)(tz / (double)N_);
    }
    __syncthreads();
    const float mx = bmx, my = bmy, mz = bmz;

    // initial farthest = argmax distance-to-mean
    float v = -1.0f; int bi = 0x7fffffff;
    float bx = 0.f, by = 0.f, bz = 0.f;
#pragma unroll
    for (int r = 0; r < 8; ++r) {
        const float dx = lx[r] - mx, dy = ly[r] - my, dz = lz[r] - mz;
        const float d = dx * dx + dy * dy + dz * dz;
        if (d > v) { v = d; bi = tid + r * 1024; bx = lx[r]; by = ly[r]; bz = lz[r]; }
    }
    waveArgMaxC(v, bi, bx, by, bz);
    if (lane == 0) { rv[wid] = v; ri[wid] = bi; rx[wid] = bx; ry[wid] = by; rz[wid] = bz; }
    __syncthreads();
    if (tid < 64) {
        float v2 = (lane < 16) ? rv[lane] : -1.0f;
        int   i2 = (lane < 16) ? ri[lane] : 0x7fffffff;
        float x2 = (lane < 16) ? rx[lane] : 0.f;
        float y2 = (lane < 16) ? ry[lane] : 0.f;
        float z2 = (lane < 16) ? rz[lane] : 0.f;
        waveArgMaxC(v2, i2, x2, y2, z2);
        if (lane == 0) { bcv = v2; bci = i2; bcx = x2; bcy = y2; bcz = z2; }
    }
    __syncthreads();
    int   far = bci;
    float cx = bcx, cy = bcy, cz = bcz;

    float dm[8];
#pragma unroll
    for (int r = 0; r < 8; ++r) dm[r] = 1e10f;

    for (int t = 0; t < G_; ++t) {
        if (tid == 0) {
            cidx[b * G_ + t] = far;
            const size_t o = ((size_t)(b * G_ + t)) * 3;
            centers_out[o + 0] = cx;
            centers_out[o + 1] = cy;
            centers_out[o + 2] = cz;
        }
        float vv = -1.0f; int ii = 0x7fffffff;
        float vx = 0.f, vy = 0.f, vz = 0.f;
#pragma unroll
        for (int r = 0; r < 8; ++r) {
            const float dx = lx[r] - cx, dy = ly[r] - cy, dz = lz[r] - cz;
            const float d = dx * dx + dy * dy + dz * dz;
            dm[r] = fminf(dm[r], d);
            if (dm[r] > vv) { vv = dm[r]; ii = tid + r * 1024; vx = lx[r]; vy = ly[r]; vz = lz[r]; }
        }
        waveArgMaxC(vv, ii, vx, vy, vz);
        if (lane == 0) { rv[wid] = vv; ri[wid] = ii; rx[wid] = vx; ry[wid] = vy; rz[wid] = vz; }
        __syncthreads();
        if (tid < 64) {
            float v2 = (lane < 16) ? rv[lane] : -1.0f;
            int   i2 = (lane < 16) ? ri[lane] : 0x7fffffff;
            float x2 = (lane < 16) ? rx[lane] : 0.f;
            float y2 = (lane < 16) ? ry[lane] : 0.f;
            float z2 = (lane < 16) ? rz[lane] : 0.f;
            waveArgMaxC(v2, i2, x2, y2, z2);
            if (lane == 0) { bcv = v2; bci = i2; bcx = x2; bcy = y2; bcz = z2; }
        }
        __syncthreads();
        far = bci; cx = bcx; cy = bcy; cz = bcz;
    }
}

// ---------------- Kernel 2: kNN (exact top-32, reference ordering) + MLP ----------------
// One block per (b, g). 384 threads (one per output channel in phase B).

#define NPT 22  // ceil(8192 / 384)

__global__ __launch_bounds__(384) void knn_mlp_kernel(
    const float* __restrict__ xyz,
    const float* __restrict__ W1, const float* __restrict__ b1,
    const float* __restrict__ W2, const float* __restrict__ b2,
    const int* __restrict__ cidx,
    float* __restrict__ out)
{
    __shared__ __align__(16) float h_lds[K_ * H_];
    __shared__ float relx[K_], rely[K_], relz[K_];
    __shared__ int   sel[K_];
    __shared__ float rv[6];
    __shared__ int   ri[6];
    __shared__ float bcv;
    __shared__ int   bci;

    const int bg   = blockIdx.x;
    const int b    = bg >> 7;        // G_ = 128
    const int tid  = threadIdx.x;
    const int lane = tid & 63;
    const int wid  = tid >> 6;
    const float* base = xyz + (size_t)b * N_ * 3;

    const int ci = cidx[bg];
    const float cx = base[ci * 3 + 0];
    const float cy = base[ci * 3 + 1];
    const float cz = base[ci * 3 + 2];

    float d[NPT];
#pragma unroll
    for (int r = 0; r < NPT; ++r) {
        const int i = tid + r * 384;
        if (i < N_) {
            const float dx = base[i * 3 + 0] - cx;
            const float dy = base[i * 3 + 1] - cy;
            const float dz = base[i * 3 + 2] - cz;
            d[r] = dx * dx + dy * dy + dz * dz;
        } else {
            d[r] = 1e30f;
        }
    }

    // 32 rounds of block-argmin; ties -> smaller index (matches lax.top_k ordering)
    for (int kk = 0; kk < K_; ++kk) {
        float v = 1e30f; int bi = 0x7fffffff;
#pragma unroll
        for (int r = 0; r < NPT; ++r) {
            if (d[r] < v) { v = d[r]; bi = tid + r * 384; }
        }
        waveArgMinF(v, bi);
        if (lane == 0) { rv[wid] = v; ri[wid] = bi; }
        __syncthreads();
        if (tid < 64) {
            float v2 = (lane < 6) ? rv[lane] : 1e30f;
            int   i2 = (lane < 6) ? ri[lane] : 0x7fffffff;
            waveArgMinF(v2, i2);
            if (lane == 0) { bcv = v2; bci = i2; }
        }
        __syncthreads();
        const int imin = bci;
        if (tid == 0) sel[kk] = imin;
        // invalidate the winner (static register indices only)
#pragma unroll
        for (int r = 0; r < NPT; ++r) {
            if (tid + r * 384 == imin) d[r] = 1e30f;
        }
    }
    __syncthreads();

    if (tid < K_) {
        const int si = sel[tid];
        out[GIDX_OFF + (size_t)bg * K_ + tid] = (float)si;
        relx[tid] = base[si * 3 + 0] - cx;
        rely[tid] = base[si * 3 + 1] - cy;
        relz[tid] = base[si * 3 + 2] - cz;
    }
    __syncthreads();

    // h = gelu(rel @ W1 + b1), exact GELU
    for (int idx = tid; idx < K_ * H_; idx += 384) {
        const int k = idx >> 7;
        const int j = idx & 127;
        const float t = fmaf(relx[k], W1[j],
                        fmaf(rely[k], W1[H_ + j],
                        fmaf(relz[k], W1[2 * H_ + j], b1[j])));
        h_lds[idx] = 0.5f * t * (1.0f + erff(t * 0.70710678118654752f));
    }
    __syncthreads();

    // feat = h @ W2, max over K, + b2. One channel per thread.
    const int dch = tid;  // 0..383
    float acc[K_];
#pragma unroll
    for (int k = 0; k < K_; ++k) acc[k] = 0.0f;

    for (int j0 = 0; j0 < H_; j0 += 4) {
        const float w0 = W2[(j0 + 0) * D_ + dch];
        const float w1 = W2[(j0 + 1) * D_ + dch];
        const float w2 = W2[(j0 + 2) * D_ + dch];
        const float w3 = W2[(j0 + 3) * D_ + dch];
#pragma unroll
        for (int k = 0; k < K_; ++k) {
            const float4 hv = *reinterpret_cast<const float4*>(&h_lds[k * H_ + j0]);
            acc[k] = fmaf(hv.w, w3, fmaf(hv.z, w2, fmaf(hv.y, w1, fmaf(hv.x, w0, acc[k]))));
        }
    }
    float m = acc[0];
#pragma unroll
    for (int k = 1; k < K_; ++k) m = fmaxf(m, acc[k]);
    out[(size_t)bg * D_ + dch] = m + b2[dch];
}

// ---------------- launch ----------------

extern "C" void kernel_launch(void* const* d_in, const int* in_sizes, int n_in,
                              void* d_out, int out_size, void* d_ws, size_t ws_size,
                              hipStream_t stream) {
    const float* xyz = (const float*)d_in[0];
    const float* W1  = (const float*)d_in[1];
    const float* b1  = (const float*)d_in[2];
    const float* W2  = (const float*)d_in[3];
    const float* b2  = (const float*)d_in[4];
    float* out = (float*)d_out;
    int*   cidx = (int*)d_ws;

    fps_kernel<<<dim3(B_), dim3(1024), 0, stream>>>(xyz, out + CEN_OFF, cidx);
    knn_mlp_kernel<<<dim3(B_ * G_), dim3(384), 0, stream>>>(xyz, W1, b1, W2, b2, cidx, out);
}

// Round 2
// 584.041 us; speedup vs baseline: 1.8375x; 1.8375x over previous
//
#include <hip/hip_runtime.h>
#include <math.h>

#define B_ 32
#define N_ 8192
#define G_ 128
#define K_ 32
#define H_ 128
#define D_ 384
#define CAP_ 1024

#define CEN_OFF (B_ * G_ * D_)
#define GIDX_OFF (B_ * G_ * D_ + B_ * G_ * 3)

// ---------------- Kernel 1: farthest point sampling ----------------
// One block per batch, 1024 threads, 8 pts/thread in registers.
// Per round: local scan -> wave butterfly on (v,i) only -> winner lane writes
// u64 key + coords to LDS -> all threads serially max 16 keys (broadcast reads).

__global__ __launch_bounds__(1024) void fps_kernel(
    const float* __restrict__ xyz,
    float* __restrict__ centers_out,
    int* __restrict__ cidx)
{
    __shared__ double sred[3][16];
    __shared__ unsigned long long srv[16];
    __shared__ float srx[16], sry[16], srz[16];
    __shared__ float smean[3];

    const int b    = blockIdx.x;
    const int tid  = threadIdx.x;
    const int lane = tid & 63;
    const int wid  = tid >> 6;
    const float* base = xyz + (size_t)b * N_ * 3;

    float lx[8], ly[8], lz[8];
    double sx = 0.0, sy = 0.0, sz = 0.0;
#pragma unroll
    for (int r = 0; r < 8; ++r) {
        const int i = tid + r * 1024;
        lx[r] = base[i * 3 + 0];
        ly[r] = base[i * 3 + 1];
        lz[r] = base[i * 3 + 2];
        sx += lx[r]; sy += ly[r]; sz += lz[r];
    }
#pragma unroll
    for (int off = 32; off >= 1; off >>= 1) {
        sx += __shfl_xor(sx, off);
        sy += __shfl_xor(sy, off);
        sz += __shfl_xor(sz, off);
    }
    if (lane == 0) { sred[0][wid] = sx; sred[1][wid] = sy; sred[2][wid] = sz; }
    __syncthreads();
    if (tid == 0) {
        double tx = 0, ty = 0, tz = 0;
        for (int w = 0; w < 16; ++w) { tx += sred[0][w]; ty += sred[1][w]; tz += sred[2][w]; }
        smean[0] = (float)(tx / (double)N_);
        smean[1] = (float)(ty / (double)N_);
        smean[2] = (float)(tz / (double)N_);
    }
    __syncthreads();
    float cx = smean[0], cy = smean[1], cz = smean[2];

    float dm[8];
#pragma unroll
    for (int r = 0; r < 8; ++r) dm[r] = 1e10f;

    int far;

    // ---- initial: argmax distance-to-mean ----
    {
        float vv = -1.0f; int ii = 0;
#pragma unroll
        for (int r = 0; r < 8; ++r) {
            const float dx = lx[r] - cx, dy = ly[r] - cy, dz = lz[r] - cz;
            const float d = dx * dx + dy * dy + dz * dz;
            if (d > vv) { vv = d; ii = tid + r * 1024; }
        }
#pragma unroll
        for (int off = 32; off >= 1; off >>= 1) {
            const float ov = __shfl_xor(vv, off);
            const int   oi = __shfl_xor(ii, off);
            if (ov > vv || (ov == vv && oi < ii)) { vv = ov; ii = oi; }
        }
        if (lane == (ii & 63)) {
            const int rr = ii >> 10;
            float wx = lx[0], wy = ly[0], wz = lz[0];
#pragma unroll
            for (int q = 1; q < 8; ++q) { if (rr == q) { wx = lx[q]; wy = ly[q]; wz = lz[q]; } }
            srv[wid] = ((unsigned long long)__float_as_uint(vv) << 32) | (unsigned)(8191 - ii);
            srx[wid] = wx; sry[wid] = wy; srz[wid] = wz;
        }
        __syncthreads();
        unsigned long long best = srv[0];
#pragma unroll
        for (int w = 1; w < 16; ++w) { const unsigned long long o = srv[w]; if (o > best) best = o; }
        far = 8191 - (int)(best & 0xFFFFFFFFULL);
        const int ww = (far & 1023) >> 6;
        cx = srx[ww]; cy = sry[ww]; cz = srz[ww];
        __syncthreads();
    }

    for (int t = 0; t < G_; ++t) {
        if (tid == 0) {
            cidx[b * G_ + t] = far;
            const size_t o = ((size_t)(b * G_ + t)) * 3;
            centers_out[o + 0] = cx;
            centers_out[o + 1] = cy;
            centers_out[o + 2] = cz;
        }
        if (t == G_ - 1) break;

        float vv = -1.0f; int ii = 0;
#pragma unroll
        for (int r = 0; r < 8; ++r) {
            const float dx = lx[r] - cx, dy = ly[r] - cy, dz = lz[r] - cz;
            const float d = dx * dx + dy * dy + dz * dz;
            dm[r] = fminf(dm[r], d);
            if (dm[r] > vv) { vv = dm[r]; ii = tid + r * 1024; }
        }
#pragma unroll
        for (int off = 32; off >= 1; off >>= 1) {
            const float ov = __shfl_xor(vv, off);
            const int   oi = __shfl_xor(ii, off);
            if (ov > vv || (ov == vv && oi < ii)) { vv = ov; ii = oi; }
        }
        if (lane == (ii & 63)) {
            const int rr = ii >> 10;
            float wx = lx[0], wy = ly[0], wz = lz[0];
#pragma unroll
            for (int q = 1; q < 8; ++q) { if (rr == q) { wx = lx[q]; wy = ly[q]; wz = lz[q]; } }
            srv[wid] = ((unsigned long long)__float_as_uint(vv) << 32) | (unsigned)(8191 - ii);
            srx[wid] = wx; sry[wid] = wy; srz[wid] = wz;
        }
        __syncthreads();
        unsigned long long best = srv[0];
#pragma unroll
        for (int w = 1; w < 16; ++w) { const unsigned long long o = srv[w]; if (o > best) best = o; }
        far = 8191 - (int)(best & 0xFFFFFFFFULL);
        const int ww = (far & 1023) >> 6;
        cx = srx[ww]; cy = sry[ww]; cz = srz[ww];
        __syncthreads();
    }
}

// ---------------- Kernel 2: kNN via radix-threshold + rank, then MLP ----------------
// One block per (b,g), 384 threads.

#define NPT 22  // ceil(8192/384)

__global__ __launch_bounds__(384) void knn_mlp_kernel(
    const float* __restrict__ xyz,
    const float* __restrict__ W1, const float* __restrict__ b1,
    const float* __restrict__ W2, const float* __restrict__ b2,
    const int* __restrict__ cidx,
    float* __restrict__ out)
{
    __shared__ unsigned int hist[2048];               // 8 KB; reused as pmax later
    __shared__ __align__(16) float h_t[H_ * K_];      // 16 KB, layout [H][K]
    __shared__ unsigned long long ck[CAP_];           // 8 KB candidate keys (dbits<<32)|idx
    __shared__ int   ssel[K_];
    __shared__ float grx[K_], gry[K_], grz[K_];
    __shared__ int   scnt, sT;

    const int bg  = blockIdx.x;
    const int b   = bg >> 7;
    const int tid = threadIdx.x;
    const int lane = tid & 63;
    const float* base = xyz + (size_t)b * N_ * 3;

    const int ci = cidx[bg];
    const float cx = base[ci * 3 + 0];
    const float cy = base[ci * 3 + 1];
    const float cz = base[ci * 3 + 2];

    // init
    for (int i = tid; i < 2048; i += 384) hist[i] = 0u;
    if (tid == 0) scnt = 0;

    float d[NPT];
#pragma unroll
    for (int r = 0; r < NPT; ++r) {
        const int i = tid + r * 384;
        if (i < N_) {
            const float dx = base[i * 3 + 0] - cx;
            const float dy = base[i * 3 + 1] - cy;
            const float dz = base[i * 3 + 2] - cz;
            d[r] = dx * dx + dy * dy + dz * dz;
        } else {
            d[r] = 1e30f;
        }
    }
    __syncthreads();

    // histogram of top-11 bits of dist bits
#pragma unroll
    for (int r = 0; r < NPT; ++r) {
        const int i = tid + r * 384;
        if (i < N_) atomicAdd(&hist[__float_as_uint(d[r]) >> 21], 1u);
    }
    __syncthreads();

    // single-wave scan: find threshold bin T with cumcount >= K_
    if (tid < 64) {
        const uint4* h4 = (const uint4*)hist;
        unsigned c = 0;
#pragma unroll
        for (int m = 0; m < 8; ++m) {
            const uint4 v = h4[tid * 8 + m];
            c += v.x + v.y + v.z + v.w;
        }
        unsigned cum = c;
#pragma unroll
        for (int off = 1; off < 64; off <<= 1) {
            const unsigned o = __shfl_up(cum, off);
            if (lane >= off) cum += o;
        }
        const unsigned long long mask = __ballot(cum >= (unsigned)K_);
        const int chunk = __ffsll(mask) - 1;
        const unsigned prior = (chunk > 0) ? (unsigned)__shfl((int)cum, chunk - 1) : 0u;
        // refine within chunk (32 bins, lanes 0..31 meaningful)
        const unsigned h2 = hist[chunk * 32 + (lane & 31)];
        unsigned cum2 = h2;
#pragma unroll
        for (int off = 1; off < 32; off <<= 1) {
            const unsigned o = __shfl_up(cum2, off);
            if ((lane & 31) >= off) cum2 += o;
        }
        const unsigned long long mask2 = __ballot(prior + cum2 >= (unsigned)K_) & 0xFFFFFFFFULL;
        const int mbin = __ffsll(mask2) - 1;
        if (lane == 0) sT = chunk * 32 + mbin;
    }
    __syncthreads();

    // collect candidates with bin <= T
    const unsigned T = (unsigned)sT;
#pragma unroll
    for (int r = 0; r < NPT; ++r) {
        const int i = tid + r * 384;
        if (i < N_) {
            const unsigned bits = __float_as_uint(d[r]);
            if ((bits >> 21) <= T) {
                const int pos = atomicAdd(&scnt, 1);
                if (pos < CAP_) ck[pos] = ((unsigned long long)bits << 32) | (unsigned)i;
            }
        }
    }
    __syncthreads();

    // exact rank among candidates; rank < K_ -> selected slot = rank
    const int cnt = (scnt < CAP_) ? scnt : CAP_;
    for (int c = tid; c < cnt; c += 384) {
        const unsigned long long kc = ck[c];
        int rk = 0;
        for (int j = 0; j < cnt; ++j) rk += (ck[j] < kc) ? 1 : 0;
        if (rk < K_) ssel[rk] = (int)(kc & 0xFFFFFFFFULL);
    }
    __syncthreads();

    if (tid < K_) {
        const int si = ssel[tid];
        out[GIDX_OFF + (size_t)bg * K_ + tid] = (float)si;
        grx[tid] = base[si * 3 + 0] - cx;
        gry[tid] = base[si * 3 + 1] - cy;
        grz[tid] = base[si * 3 + 2] - cz;
    }
    __syncthreads();

    // h_t[j][k] = gelu(rel[k] . W1[:,j] + b1[j])
    for (int idx = tid; idx < K_ * H_; idx += 384) {
        const int k = idx & 31;
        const int j = idx >> 5;
        const float t = fmaf(grx[k], W1[j],
                        fmaf(gry[k], W1[H_ + j],
                        fmaf(grz[k], W1[2 * H_ + j], b1[j])));
        h_t[idx] = 0.5f * t * (1.0f + erff(t * 0.70710678118654752f));
    }
    __syncthreads();

    // GEMM: thread = (k-quarter, 4 channels). acc[8][4] over j=0..127.
    const int kq  = tid / 96;       // 0..3 -> k in [kq*8, kq*8+8)
    const int cg  = tid % 96;
    const int ch0 = cg * 4;
    const float* W2r = W2 + ch0;

    float acc[8][4];
#pragma unroll
    for (int kk = 0; kk < 8; ++kk)
#pragma unroll
        for (int cc = 0; cc < 4; ++cc) acc[kk][cc] = 0.0f;

#pragma unroll 2
    for (int j = 0; j < H_; ++j) {
        const float4 w  = *(const float4*)(W2r + j * D_);
        const float4 ha = *(const float4*)(&h_t[(j << 5) + kq * 8]);
        const float4 hb = *(const float4*)(&h_t[(j << 5) + kq * 8 + 4]);
        const float h0 = ha.x, h1 = ha.y, h2 = ha.z, h3 = ha.w;
        const float h4 = hb.x, h5 = hb.y, h6 = hb.z, h7 = hb.w;
#define FMA4(KK, HV) \
        acc[KK][0] = fmaf(HV, w.x, acc[KK][0]); \
        acc[KK][1] = fmaf(HV, w.y, acc[KK][1]); \
        acc[KK][2] = fmaf(HV, w.z, acc[KK][2]); \
        acc[KK][3] = fmaf(HV, w.w, acc[KK][3]);
        FMA4(0, h0) FMA4(1, h1) FMA4(2, h2) FMA4(3, h3)
        FMA4(4, h4) FMA4(5, h5) FMA4(6, h6) FMA4(7, h7)
#undef FMA4
    }

    // per-thread max over its 8 k's, then cross-kq reduce via LDS (reuse hist)
    float* pmax = (float*)hist;
    float4 mv;
    mv.x = acc[0][0]; mv.y = acc[0][1]; mv.z = acc[0][2]; mv.w = acc[0][3];
#pragma unroll
    for (int kk = 1; kk < 8; ++kk) {
        mv.x = fmaxf(mv.x, acc[kk][0]);
        mv.y = fmaxf(mv.y, acc[kk][1]);
        mv.z = fmaxf(mv.z, acc[kk][2]);
        mv.w = fmaxf(mv.w, acc[kk][3]);
    }
    *(float4*)&pmax[kq * D_ + ch0] = mv;
    __syncthreads();

    const float v = fmaxf(fmaxf(pmax[tid], pmax[D_ + tid]),
                          fmaxf(pmax[2 * D_ + tid], pmax[3 * D_ + tid])) + b2[tid];
    out[(size_t)bg * D_ + tid] = v;
}

// ---------------- launch ----------------

extern "C" void kernel_launch(void* const* d_in, const int* in_sizes, int n_in,
                              void* d_out, int out_size, void* d_ws, size_t ws_size,
                              hipStream_t stream) {
    const float* xyz = (const float*)d_in[0];
    const float* W1  = (const float*)d_in[1];
    const float* b1  = (const float*)d_in[2];
    const float* W2  = (const float*)d_in[3];
    const float* b2  = (const float*)d_in[4];
    float* out = (float*)d_out;
    int*   cidx = (int*)d_ws;

    fps_kernel<<<dim3(B_), dim3(1024), 0, stream>>>(xyz, out + CEN_OFF, cidx);
    knn_mlp_kernel<<<dim3(B_ * G_), dim3(384), 0, stream>>>(xyz, W1, b1, W2, b2, cidx, out);
}

// Round 3
// 411.262 us; speedup vs baseline: 2.6095x; 1.4201x over previous
//
#include <hip/hip_runtime.h>
#include <math.h>

#define B_ 32
#define N_ 8192
#define G_ 128
#define K_ 32
#define H_ 128
#define D_ 384
#define CAP_ 1024

#define CEN_OFF (B_ * G_ * D_)
#define GIDX_OFF (B_ * G_ * D_ + B_ * G_ * 3)

// ---------------- Kernel 1: farthest point sampling ----------------
// One block per batch, 512 threads (8 waves), 16 pts/thread in registers.
// Per round: local scan -> wave butterfly on (v,i) -> lane0 atomicMax(u64 key)
// into a triple-buffered LDS slot -> ONE barrier -> all read 1 u64 + uniform
// global load of winner coords. Reference argmax semantics: max dist, ties ->
// lowest index (key packs 8191-idx).

#define FPT 16  // points per thread (8192 / 512)

__global__ __launch_bounds__(512) void fps_kernel(
    const float* __restrict__ xyz,
    float* __restrict__ centers_out,
    int* __restrict__ cidx)
{
    __shared__ double sred[3][8];
    __shared__ float smean[3];
    __shared__ unsigned long long skey[3];

    const int b    = blockIdx.x;
    const int tid  = threadIdx.x;
    const int lane = tid & 63;
    const int wid  = tid >> 6;
    const float* base = xyz + (size_t)b * N_ * 3;

    float lx[FPT], ly[FPT], lz[FPT];
    double sx = 0.0, sy = 0.0, sz = 0.0;
#pragma unroll
    for (int r = 0; r < FPT; ++r) {
        const int i = tid + r * 512;
        lx[r] = base[i * 3 + 0];
        ly[r] = base[i * 3 + 1];
        lz[r] = base[i * 3 + 2];
        sx += lx[r]; sy += ly[r]; sz += lz[r];
    }
#pragma unroll
    for (int off = 32; off >= 1; off >>= 1) {
        sx += __shfl_xor(sx, off);
        sy += __shfl_xor(sy, off);
        sz += __shfl_xor(sz, off);
    }
    if (lane == 0) { sred[0][wid] = sx; sred[1][wid] = sy; sred[2][wid] = sz; }
    if (tid == 0) { skey[0] = 0ULL; skey[1] = 0ULL; skey[2] = 0ULL; }
    __syncthreads();
    if (tid == 0) {
        double tx = 0, ty = 0, tz = 0;
        for (int w = 0; w < 8; ++w) { tx += sred[0][w]; ty += sred[1][w]; tz += sred[2][w]; }
        smean[0] = (float)(tx / (double)N_);
        smean[1] = (float)(ty / (double)N_);
        smean[2] = (float)(tz / (double)N_);
    }
    __syncthreads();
    float cx = smean[0], cy = smean[1], cz = smean[2];

    float dm[FPT];
#pragma unroll
    for (int r = 0; r < FPT; ++r) dm[r] = 1e10f;

    int far;

    // ---- initial: argmax distance-to-mean (slot 2) ----
    {
        float vv = -1.0f; int ii = 0;
#pragma unroll
        for (int r = 0; r < FPT; ++r) {
            const float dx = lx[r] - cx, dy = ly[r] - cy, dz = lz[r] - cz;
            const float d = dx * dx + dy * dy + dz * dz;
            if (d > vv) { vv = d; ii = tid + r * 512; }
        }
#pragma unroll
        for (int off = 32; off >= 1; off >>= 1) {
            const float ov = __shfl_xor(vv, off);
            const int   oi = __shfl_xor(ii, off);
            if (ov > vv || (ov == vv && oi < ii)) { vv = ov; ii = oi; }
        }
        if (lane == 0) {
            const unsigned long long key =
                ((unsigned long long)__float_as_uint(vv) << 32) | (unsigned)(8191 - ii);
            atomicMax(&skey[2], key);
        }
        __syncthreads();
        const unsigned long long best = skey[2];
        far = 8191 - (int)(best & 0xFFFFFFFFULL);
        cx = base[far * 3 + 0];
        cy = base[far * 3 + 1];
        cz = base[far * 3 + 2];
    }

    for (int t = 0; t < G_; ++t) {
        if (tid == 0) {
            cidx[b * G_ + t] = far;
            const size_t o = ((size_t)(b * G_ + t)) * 3;
            centers_out[o + 0] = cx;
            centers_out[o + 1] = cy;
            centers_out[o + 2] = cz;
        }
        if (t == G_ - 1) break;

        float vv = -1.0f; int ii = 0;
#pragma unroll
        for (int r = 0; r < FPT; ++r) {
            const float dx = lx[r] - cx, dy = ly[r] - cy, dz = lz[r] - cz;
            const float d = dx * dx + dy * dy + dz * dz;
            dm[r] = fminf(dm[r], d);
            if (dm[r] > vv) { vv = dm[r]; ii = tid + r * 512; }
        }
#pragma unroll
        for (int off = 32; off >= 1; off >>= 1) {
            const float ov = __shfl_xor(vv, off);
            const int   oi = __shfl_xor(ii, off);
            if (ov > vv || (ov == vv && oi < ii)) { vv = ov; ii = oi; }
        }
        if (lane == 0) {
            const unsigned long long key =
                ((unsigned long long)__float_as_uint(vv) << 32) | (unsigned)(8191 - ii);
            atomicMax(&skey[t % 3], key);
        }
        // reset the slot round t+1 will use; last touched in round t-2's
        // post-barrier reads, which completed before barrier t-1.
        if (tid == 0) skey[(t + 1) % 3] = 0ULL;
        __syncthreads();
        const unsigned long long best = skey[t % 3];
        far = 8191 - (int)(best & 0xFFFFFFFFULL);
        cx = base[far * 3 + 0];
        cy = base[far * 3 + 1];
        cz = base[far * 3 + 2];
    }
}

// ---------------- Kernel 2: kNN via radix-threshold + rank, then MLP ----------------
// One block per (b,g), 384 threads. (unchanged from round 2)

#define NPT 22  // ceil(8192/384)

__global__ __launch_bounds__(384) void knn_mlp_kernel(
    const float* __restrict__ xyz,
    const float* __restrict__ W1, const float* __restrict__ b1,
    const float* __restrict__ W2, const float* __restrict__ b2,
    const int* __restrict__ cidx,
    float* __restrict__ out)
{
    __shared__ unsigned int hist[2048];               // 8 KB; reused as pmax later
    __shared__ __align__(16) float h_t[H_ * K_];      // 16 KB, layout [H][K]
    __shared__ unsigned long long ck[CAP_];           // 8 KB candidate keys (dbits<<32)|idx
    __shared__ int   ssel[K_];
    __shared__ float grx[K_], gry[K_], grz[K_];
    __shared__ int   scnt, sT;

    const int bg  = blockIdx.x;
    const int b   = bg >> 7;
    const int tid = threadIdx.x;
    const int lane = tid & 63;
    const float* base = xyz + (size_t)b * N_ * 3;

    const int ci = cidx[bg];
    const float cx = base[ci * 3 + 0];
    const float cy = base[ci * 3 + 1];
    const float cz = base[ci * 3 + 2];

    for (int i = tid; i < 2048; i += 384) hist[i] = 0u;
    if (tid == 0) scnt = 0;

    float d[NPT];
#pragma unroll
    for (int r = 0; r < NPT; ++r) {
        const int i = tid + r * 384;
        if (i < N_) {
            const float dx = base[i * 3 + 0] - cx;
            const float dy = base[i * 3 + 1] - cy;
            const float dz = base[i * 3 + 2] - cz;
            d[r] = dx * dx + dy * dy + dz * dz;
        } else {
            d[r] = 1e30f;
        }
    }
    __syncthreads();

#pragma unroll
    for (int r = 0; r < NPT; ++r) {
        const int i = tid + r * 384;
        if (i < N_) atomicAdd(&hist[__float_as_uint(d[r]) >> 21], 1u);
    }
    __syncthreads();

    if (tid < 64) {
        const uint4* h4 = (const uint4*)hist;
        unsigned c = 0;
#pragma unroll
        for (int m = 0; m < 8; ++m) {
            const uint4 v = h4[tid * 8 + m];
            c += v.x + v.y + v.z + v.w;
        }
        unsigned cum = c;
#pragma unroll
        for (int off = 1; off < 64; off <<= 1) {
            const unsigned o = __shfl_up(cum, off);
            if (lane >= off) cum += o;
        }
        const unsigned long long mask = __ballot(cum >= (unsigned)K_);
        const int chunk = __ffsll(mask) - 1;
        const unsigned prior = (chunk > 0) ? (unsigned)__shfl((int)cum, chunk - 1) : 0u;
        const unsigned h2 = hist[chunk * 32 + (lane & 31)];
        unsigned cum2 = h2;
#pragma unroll
        for (int off = 1; off < 32; off <<= 1) {
            const unsigned o = __shfl_up(cum2, off);
            if ((lane & 31) >= off) cum2 += o;
        }
        const unsigned long long mask2 = __ballot(prior + cum2 >= (unsigned)K_) & 0xFFFFFFFFULL;
        const int mbin = __ffsll(mask2) - 1;
        if (lane == 0) sT = chunk * 32 + mbin;
    }
    __syncthreads();

    const unsigned T = (unsigned)sT;
#pragma unroll
    for (int r = 0; r < NPT; ++r) {
        const int i = tid + r * 384;
        if (i < N_) {
            const unsigned bits = __float_as_uint(d[r]);
            if ((bits >> 21) <= T) {
                const int pos = atomicAdd(&scnt, 1);
                if (pos < CAP_) ck[pos] = ((unsigned long long)bits << 32) | (unsigned)i;
            }
        }
    }
    __syncthreads();

    const int cnt = (scnt < CAP_) ? scnt : CAP_;
    for (int c = tid; c < cnt; c += 384) {
        const unsigned long long kc = ck[c];
        int rk = 0;
        for (int j = 0; j < cnt; ++j) rk += (ck[j] < kc) ? 1 : 0;
        if (rk < K_) ssel[rk] = (int)(kc & 0xFFFFFFFFULL);
    }
    __syncthreads();

    if (tid < K_) {
        const int si = ssel[tid];
        out[GIDX_OFF + (size_t)bg * K_ + tid] = (float)si;
        grx[tid] = base[si * 3 + 0] - cx;
        gry[tid] = base[si * 3 + 1] - cy;
        grz[tid] = base[si * 3 + 2] - cz;
    }
    __syncthreads();

    for (int idx = tid; idx < K_ * H_; idx += 384) {
        const int k = idx & 31;
        const int j = idx >> 5;
        const float t = fmaf(grx[k], W1[j],
                        fmaf(gry[k], W1[H_ + j],
                        fmaf(grz[k], W1[2 * H_ + j], b1[j])));
        h_t[idx] = 0.5f * t * (1.0f + erff(t * 0.70710678118654752f));
    }
    __syncthreads();

    const int kq  = tid / 96;
    const int cg  = tid % 96;
    const int ch0 = cg * 4;
    const float* W2r = W2 + ch0;

    float acc[8][4];
#pragma unroll
    for (int kk = 0; kk < 8; ++kk)
#pragma unroll
        for (int cc = 0; cc < 4; ++cc) acc[kk][cc] = 0.0f;

#pragma unroll 2
    for (int j = 0; j < H_; ++j) {
        const float4 w  = *(const float4*)(W2r + j * D_);
        const float4 ha = *(const float4*)(&h_t[(j << 5) + kq * 8]);
        const float4 hb = *(const float4*)(&h_t[(j << 5) + kq * 8 + 4]);
        const float h0 = ha.x, h1 = ha.y, h2 = ha.z, h3 = ha.w;
        const float h4 = hb.x, h5 = hb.y, h6 = hb.z, h7 = hb.w;
#define FMA4(KK, HV) \
        acc[KK][0] = fmaf(HV, w.x, acc[KK][0]); \
        acc[KK][1] = fmaf(HV, w.y, acc[KK][1]); \
        acc[KK][2] = fmaf(HV, w.z, acc[KK][2]); \
        acc[KK][3] = fmaf(HV, w.w, acc[KK][3]);
        FMA4(0, h0) FMA4(1, h1) FMA4(2, h2) FMA4(3, h3)
        FMA4(4, h4) FMA4(5, h5) FMA4(6, h6) FMA4(7, h7)
#undef FMA4
    }

    float* pmax = (float*)hist;
    float4 mv;
    mv.x = acc[0][0]; mv.y = acc[0][1]; mv.z = acc[0][2]; mv.w = acc[0][3];
#pragma unroll
    for (int kk = 1; kk < 8; ++kk) {
        mv.x = fmaxf(mv.x, acc[kk][0]);
        mv.y = fmaxf(mv.y, acc[kk][1]);
        mv.z = fmaxf(mv.z, acc[kk][2]);
        mv.w = fmaxf(mv.w, acc[kk][3]);
    }
    *(float4*)&pmax[kq * D_ + ch0] = mv;
    __syncthreads();

    const float v = fmaxf(fmaxf(pmax[tid], pmax[D_ + tid]),
                          fmaxf(pmax[2 * D_ + tid], pmax[3 * D_ + tid])) + b2[tid];
    out[(size_t)bg * D_ + tid] = v;
}

// ---------------- launch ----------------

extern "C" void kernel_launch(void* const* d_in, const int* in_sizes, int n_in,
                              void* d_out, int out_size, void* d_ws, size_t ws_size,
                              hipStream_t stream) {
    const float* xyz = (const float*)d_in[0];
    const float* W1  = (const float*)d_in[1];
    const float* b1  = (const float*)d_in[2];
    const float* W2  = (const float*)d_in[3];
    const float* b2  = (const float*)d_in[4];
    float* out = (float*)d_out;
    int*   cidx = (int*)d_ws;

    fps_kernel<<<dim3(B_), dim3(512), 0, stream>>>(xyz, out + CEN_OFF, cidx);
    knn_mlp_kernel<<<dim3(B_ * G_), dim3(384), 0, stream>>>(xyz, W1, b1, W2, b2, cidx, out);
}

// Round 4
// 334.649 us; speedup vs baseline: 3.2069x; 1.2289x over previous
//
#include <hip/hip_runtime.h>
#include <math.h>

#define B_ 32
#define N_ 8192
#define G_ 128
#define K_ 32
#define H_ 128
#define D_ 384
#define CAP_ 1024

#define CEN_OFF (B_ * G_ * D_)
#define GIDX_OFF (B_ * G_ * D_ + B_ * G_ * 3)

typedef short bf16x8 __attribute__((ext_vector_type(8)));
typedef float f32x4 __attribute__((ext_vector_type(4)));

__device__ __forceinline__ unsigned short f2bf(float x) {
    unsigned u = __float_as_uint(x);
    u += 0x7FFFu + ((u >> 16) & 1u);
    return (unsigned short)(u >> 16);
}
__device__ __forceinline__ float bf2f(unsigned short h) {
    return __uint_as_float(((unsigned)h) << 16);
}

// ---------------- Kernel 1: FPS (blocks 0..31) + W2 fragment prep (blocks 32..127) ----
// FPS: 512 threads, 16 pts/thread in registers. Per round: payload-carrying
// argmax (coords ride the butterfly), per-wave LDS slot write, ONE barrier,
// 8-slot tree-max; parity-double-buffered slots. No atomics, no global fetch
// in the serial chain.

#define FPT 16

__global__ __launch_bounds__(512) void fps_prep_kernel(
    const float* __restrict__ xyz,
    const float* __restrict__ W2,
    float* __restrict__ centers_out,
    int* __restrict__ cidx,
    unsigned short* __restrict__ w2hi,
    unsigned short* __restrict__ w2lo)
{
    if (blockIdx.x >= B_) {
        // ---- W2 -> hi/lo bf16 fragments, MFMA B-layout ----
        const int idx = (blockIdx.x - B_) * 512 + threadIdx.x;   // 0..49151 row-major (j,c)
        const float w = W2[idx];
        const unsigned short hi = f2bf(w);
        const unsigned short lo = f2bf(w - bf2f(hi));
        const int j = idx / D_;
        const int c = idx - j * D_;
        const int l = (c & 15) | (((j >> 3) & 3) << 4);
        const int o = ((c >> 4) * 4 + (j >> 5)) * 512 + l * 8 + (j & 7);
        w2hi[o] = hi;
        w2lo[o] = lo;
        return;
    }

    __shared__ double sred[3][8];
    __shared__ float smean[3];
    __shared__ unsigned long long wkey[2][8];
    __shared__ float wcx[2][8], wcy[2][8], wcz[2][8];

    const int b    = blockIdx.x;
    const int tid  = threadIdx.x;
    const int lane = tid & 63;
    const int wid  = tid >> 6;
    const float* base = xyz + (size_t)b * N_ * 3;

    float lx[FPT], ly[FPT], lz[FPT];
    double sx = 0.0, sy = 0.0, sz = 0.0;
#pragma unroll
    for (int r = 0; r < FPT; ++r) {
        const int i = tid + r * 512;
        lx[r] = base[i * 3 + 0];
        ly[r] = base[i * 3 + 1];
        lz[r] = base[i * 3 + 2];
        sx += lx[r]; sy += ly[r]; sz += lz[r];
    }
#pragma unroll
    for (int off = 32; off >= 1; off >>= 1) {
        sx += __shfl_xor(sx, off);
        sy += __shfl_xor(sy, off);
        sz += __shfl_xor(sz, off);
    }
    if (lane == 0) { sred[0][wid] = sx; sred[1][wid] = sy; sred[2][wid] = sz; }
    __syncthreads();
    if (tid == 0) {
        double tx = 0, ty = 0, tz = 0;
        for (int w = 0; w < 8; ++w) { tx += sred[0][w]; ty += sred[1][w]; tz += sred[2][w]; }
        smean[0] = (float)(tx / (double)N_);
        smean[1] = (float)(ty / (double)N_);
        smean[2] = (float)(tz / (double)N_);
    }
    __syncthreads();
    float cx = smean[0], cy = smean[1], cz = smean[2];

    float dm[FPT];
#pragma unroll
    for (int r = 0; r < FPT; ++r) dm[r] = 1e10f;

    int far;

    // ---- initial round: argmax dist-to-mean (parity slot 1) ----
    {
        float vv = -1.0f; int ii = 0;
        float px = lx[0], py = ly[0], pz = lz[0];
#pragma unroll
        for (int r = 0; r < FPT; ++r) {
            const float dx = lx[r] - cx, dy = ly[r] - cy, dz = lz[r] - cz;
            const float d = dx * dx + dy * dy + dz * dz;
            if (d > vv) { vv = d; ii = tid + r * 512; px = lx[r]; py = ly[r]; pz = lz[r]; }
        }
#pragma unroll
        for (int off = 32; off >= 1; off >>= 1) {
            const float ov = __shfl_xor(vv, off);
            const int   oi = __shfl_xor(ii, off);
            const float ox = __shfl_xor(px, off);
            const float oy = __shfl_xor(py, off);
            const float oz = __shfl_xor(pz, off);
            if (ov > vv || (ov == vv && oi < ii)) { vv = ov; ii = oi; px = ox; py = oy; pz = oz; }
        }
        if (lane == 0) {
            wkey[1][wid] = ((unsigned long long)__float_as_uint(vv) << 32) | (unsigned)(8191 - ii);
            wcx[1][wid] = px; wcy[1][wid] = py; wcz[1][wid] = pz;
        }
        __syncthreads();
        unsigned long long bk = wkey[1][0]; int bs = 0;
#pragma unroll
        for (int s = 1; s < 8; ++s) {
            const unsigned long long k = wkey[1][s];
            if (k > bk) { bk = k; bs = s; }
        }
        far = 8191 - (int)(bk & 0xFFFFFFFFULL);
        cx = wcx[1][bs]; cy = wcy[1][bs]; cz = wcz[1][bs];
    }

    for (int t = 0; t < G_; ++t) {
        if (tid == 0) {
            cidx[b * G_ + t] = far;
            const size_t o = ((size_t)(b * G_ + t)) * 3;
            centers_out[o + 0] = cx;
            centers_out[o + 1] = cy;
            centers_out[o + 2] = cz;
        }
        if (t == G_ - 1) break;
        const int p = t & 1;

        float vv = -1.0f; int ii = 0;
        float px = lx[0], py = ly[0], pz = lz[0];
#pragma unroll
        for (int r = 0; r < FPT; ++r) {
            const float dx = lx[r] - cx, dy = ly[r] - cy, dz = lz[r] - cz;
            const float d = dx * dx + dy * dy + dz * dz;
            dm[r] = fminf(dm[r], d);
            if (dm[r] > vv) { vv = dm[r]; ii = tid + r * 512; px = lx[r]; py = ly[r]; pz = lz[r]; }
        }
#pragma unroll
        for (int off = 32; off >= 1; off >>= 1) {
            const float ov = __shfl_xor(vv, off);
            const int   oi = __shfl_xor(ii, off);
            const float ox = __shfl_xor(px, off);
            const float oy = __shfl_xor(py, off);
            const float oz = __shfl_xor(pz, off);
            if (ov > vv || (ov == vv && oi < ii)) { vv = ov; ii = oi; px = ox; py = oy; pz = oz; }
        }
        if (lane == 0) {
            wkey[p][wid] = ((unsigned long long)__float_as_uint(vv) << 32) | (unsigned)(8191 - ii);
            wcx[p][wid] = px; wcy[p][wid] = py; wcz[p][wid] = pz;
        }
        __syncthreads();
        unsigned long long bk = wkey[p][0]; int bs = 0;
#pragma unroll
        for (int s = 1; s < 8; ++s) {
            const unsigned long long k = wkey[p][s];
            if (k > bk) { bk = k; bs = s; }
        }
        far = 8191 - (int)(bk & 0xFFFFFFFFULL);
        cx = wcx[p][bs]; cy = wcy[p][bs]; cz = wcz[p][bs];
    }
}

// ---------------- Kernel 2: kNN (radix-threshold + rank) + MFMA MLP ----------------
// 512 threads (8 waves) per (b,g) block.

#define NPT 16  // 8192/512

__global__ __launch_bounds__(512) void knn_mlp_kernel(
    const float* __restrict__ xyz,
    const float* __restrict__ W1, const float* __restrict__ b1,
    const float* __restrict__ b2,
    const int* __restrict__ cidx,
    const unsigned short* __restrict__ w2hi,
    const unsigned short* __restrict__ w2lo,
    float* __restrict__ out)
{
    __shared__ unsigned int hist[2048];
    __shared__ unsigned long long ck[CAP_];
    __shared__ __align__(16) unsigned short AHi[4096];
    __shared__ __align__(16) unsigned short ALo[4096];
    __shared__ float sW1[384], sb1[128];
    __shared__ float relx[K_], rely[K_], relz[K_];
    __shared__ int   ssel[K_];
    __shared__ int   scnt, sT;

    const int bg   = blockIdx.x;
    const int b    = bg >> 7;
    const int tid  = threadIdx.x;
    const int lane = tid & 63;
    const int wid  = tid >> 6;
    const float* base = xyz + (size_t)b * N_ * 3;

    const int ci = cidx[bg];
    const float cx = base[ci * 3 + 0];
    const float cy = base[ci * 3 + 1];
    const float cz = base[ci * 3 + 2];

    for (int i = tid; i < 2048; i += 512) hist[i] = 0u;
    if (tid < 384) sW1[tid] = W1[tid];
    else if (tid < 512 && tid >= 384) sb1[tid - 384] = b1[tid - 384];
    if (tid == 0) scnt = 0;

    float d[NPT];
#pragma unroll
    for (int r = 0; r < NPT; ++r) {
        const int i = tid + r * 512;
        const float dx = base[i * 3 + 0] - cx;
        const float dy = base[i * 3 + 1] - cy;
        const float dz = base[i * 3 + 2] - cz;
        d[r] = dx * dx + dy * dy + dz * dz;
    }
    __syncthreads();

#pragma unroll
    for (int r = 0; r < NPT; ++r) atomicAdd(&hist[__float_as_uint(d[r]) >> 21], 1u);
    __syncthreads();

    if (tid < 64) {
        const uint4* h4 = (const uint4*)hist;
        unsigned c = 0;
#pragma unroll
        for (int m = 0; m < 8; ++m) {
            const uint4 v = h4[tid * 8 + m];
            c += v.x + v.y + v.z + v.w;
        }
        unsigned cum = c;
#pragma unroll
        for (int off = 1; off < 64; off <<= 1) {
            const unsigned o = __shfl_up(cum, off);
            if (lane >= off) cum += o;
        }
        const unsigned long long mask = __ballot(cum >= (unsigned)K_);
        const int chunk = __ffsll(mask) - 1;
        const unsigned prior = (chunk > 0) ? (unsigned)__shfl((int)cum, chunk - 1) : 0u;
        const unsigned h2 = hist[chunk * 32 + (lane & 31)];
        unsigned cum2 = h2;
#pragma unroll
        for (int off = 1; off < 32; off <<= 1) {
            const unsigned o = __shfl_up(cum2, off);
            if ((lane & 31) >= off) cum2 += o;
        }
        const unsigned long long mask2 = __ballot(prior + cum2 >= (unsigned)K_) & 0xFFFFFFFFULL;
        const int mbin = __ffsll(mask2) - 1;
        if (lane == 0) sT = chunk * 32 + mbin;
    }
    __syncthreads();

    const unsigned T = (unsigned)sT;
#pragma unroll
    for (int r = 0; r < NPT; ++r) {
        const unsigned bits = __float_as_uint(d[r]);
        if ((bits >> 21) <= T) {
            const int pos = atomicAdd(&scnt, 1);
            if (pos < CAP_) ck[pos] = ((unsigned long long)bits << 32) | (unsigned)(tid + r * 512);
        }
    }
    __syncthreads();

    const int cnt = (scnt < CAP_) ? scnt : CAP_;
    for (int c = tid; c < cnt; c += 512) {
        const unsigned long long kc = ck[c];
        int rk = 0;
        for (int j = 0; j < cnt; ++j) rk += (ck[j] < kc) ? 1 : 0;
        if (rk < K_) ssel[rk] = (int)(kc & 0xFFFFFFFFULL);
    }
    __syncthreads();

    if (tid < K_) {
        const int si = ssel[tid];
        out[GIDX_OFF + (size_t)bg * K_ + tid] = (float)si;
        relx[tid] = base[si * 3 + 0] - cx;
        rely[tid] = base[si * 3 + 1] - cy;
        relz[tid] = base[si * 3 + 2] - cz;
    }
    __syncthreads();

    // ---- h = gelu(rel@W1+b1), computed directly in A-fragment layout ----
    // pair p = wid: m = p>>2, kb = p&3. lane covers row = m*16+(lane&15),
    // j = kb*32 + (lane>>4)*8 + e, e=0..7. One ds_write_b128 each for hi/lo.
    {
        const int p  = wid;
        const int row = ((p >> 2) << 4) + (lane & 15);
        const int j0 = ((p & 3) << 5) + (((lane >> 4) & 3) << 3);
        const float rx = relx[row], ry = rely[row], rz = relz[row];
        bf16x8 hv, lv;
#pragma unroll
        for (int e = 0; e < 8; ++e) {
            const int j = j0 + e;
            const float t = fmaf(rx, sW1[j], fmaf(ry, sW1[128 + j], fmaf(rz, sW1[256 + j], sb1[j])));
            const float g = 0.5f * t * (1.0f + erff(t * 0.70710678118654752f));
            const unsigned short hi = f2bf(g);
            hv[e] = (short)hi;
            lv[e] = (short)f2bf(g - bf2f(hi));
        }
        *(bf16x8*)&AHi[p * 512 + lane * 8] = hv;
        *(bf16x8*)&ALo[p * 512 + lane * 8] = lv;
    }
    __syncthreads();

    // ---- MFMA GEMM: wave w owns N-tiles {3w, 3w+1, 3w+2} ----
    bf16x8 ah[8], al[8];
#pragma unroll
    for (int p = 0; p < 8; ++p) {
        ah[p] = *(const bf16x8*)&AHi[p * 512 + lane * 8];
        al[p] = *(const bf16x8*)&ALo[p * 512 + lane * 8];
    }

#pragma unroll
    for (int nn = 0; nn < 3; ++nn) {
        const int n = wid * 3 + nn;
        f32x4 acc0 = {0.f, 0.f, 0.f, 0.f};
        f32x4 acc1 = {0.f, 0.f, 0.f, 0.f};
#pragma unroll
        for (int kb = 0; kb < 4; ++kb) {
            const int off = (n * 4 + kb) * 512 + lane * 8;
            const bf16x8 bh = *(const bf16x8*)&w2hi[off];
            const bf16x8 bl = *(const bf16x8*)&w2lo[off];
            acc0 = __builtin_amdgcn_mfma_f32_16x16x32_bf16(ah[kb], bh, acc0, 0, 0, 0);
            acc0 = __builtin_amdgcn_mfma_f32_16x16x32_bf16(ah[kb], bl, acc0, 0, 0, 0);
            acc0 = __builtin_amdgcn_mfma_f32_16x16x32_bf16(al[kb], bh, acc0, 0, 0, 0);
            acc1 = __builtin_amdgcn_mfma_f32_16x16x32_bf16(ah[4 + kb], bh, acc1, 0, 0, 0);
            acc1 = __builtin_amdgcn_mfma_f32_16x16x32_bf16(ah[4 + kb], bl, acc1, 0, 0, 0);
            acc1 = __builtin_amdgcn_mfma_f32_16x16x32_bf16(al[4 + kb], bh, acc1, 0, 0, 0);
        }
        // col = n*16 + (lane&15); rows covered: acc0 -> 0..15, acc1 -> 16..31
        float cm = fmaxf(fmaxf(fmaxf(acc0[0], acc0[1]), fmaxf(acc0[2], acc0[3])),
                         fmaxf(fmaxf(acc1[0], acc1[1]), fmaxf(acc1[2], acc1[3])));
        cm = fmaxf(cm, __shfl_xor(cm, 16));
        cm = fmaxf(cm, __shfl_xor(cm, 32));
        if (lane < 16) {
            const int col = n * 16 + lane;
            out[(size_t)bg * D_ + col] = cm + b2[col];
        }
    }
}

// ---------------- launch ----------------

extern "C" void kernel_launch(void* const* d_in, const int* in_sizes, int n_in,
                              void* d_out, int out_size, void* d_ws, size_t ws_size,
                              hipStream_t stream) {
    const float* xyz = (const float*)d_in[0];
    const float* W1  = (const float*)d_in[1];
    const float* b1  = (const float*)d_in[2];
    const float* W2  = (const float*)d_in[3];
    const float* b2  = (const float*)d_in[4];
    float* out = (float*)d_out;

    char* ws = (char*)d_ws;
    int* cidx = (int*)ws;                                        // 16384 B
    unsigned short* w2hi = (unsigned short*)(ws + 16384);        // 98304 B
    unsigned short* w2lo = (unsigned short*)(ws + 16384 + 98304);// 98304 B

    // blocks 0..31: FPS; blocks 32..127: W2 fragment prep (49152 elems / 512)
    fps_prep_kernel<<<dim3(B_ + 96), dim3(512), 0, stream>>>(xyz, W2, out + CEN_OFF, cidx, w2hi, w2lo);
    knn_mlp_kernel<<<dim3(B_ * G_), dim3(512), 0, stream>>>(xyz, W1, b1, b2, cidx, w2hi, w2lo, out);
}

// Round 5
// 325.904 us; speedup vs baseline: 3.2929x; 1.0268x over previous
//
#include <hip/hip_runtime.h>
#include <math.h>

#define B_ 32
#define N_ 8192
#define G_ 128
#define K_ 32
#define H_ 128
#define D_ 384
#define CAP_ 1024

#define CEN_OFF (B_ * G_ * D_)
#define GIDX_OFF (B_ * G_ * D_ + B_ * G_ * 3)

typedef short bf16x8 __attribute__((ext_vector_type(8)));
typedef float f32x4 __attribute__((ext_vector_type(4)));

__device__ __forceinline__ unsigned short f2bf(float x) {
    unsigned u = __float_as_uint(x);
    u += 0x7FFFu + ((u >> 16) & 1u);
    return (unsigned short)(u >> 16);
}
__device__ __forceinline__ float bf2f(unsigned short h) {
    return __uint_as_float(((unsigned)h) << 16);
}

// ---------------- Kernel 1: FPS (blocks 0..31) + W2 fragment prep (blocks 32..223) ----
// FPS: 256 threads (4 waves, 1/SIMD), 32 pts/thread in registers.
// Scan tracks (vv, ii, px,py,pz) per thread; butterfly reduces (vv,ii) ONLY
// (payload off the shuffle chain); the wave-winning LANE writes key+coords to
// its wave's slot (it owns the coords in registers); one barrier; all threads
// read 4 keys + 4 coord-float4s in parallel and select uniformly.
// Slots are parity-double-buffered (WAR separated by the round barrier).

#define FPT 32

__global__ __launch_bounds__(256) void fps_prep_kernel(
    const float* __restrict__ xyz,
    const float* __restrict__ W2,
    float* __restrict__ centers_out,
    int* __restrict__ cidx,
    unsigned short* __restrict__ w2hi,
    unsigned short* __restrict__ w2lo)
{
    if (blockIdx.x >= B_) {
        // ---- W2 -> hi/lo bf16 fragments, MFMA B-layout (proven round 4) ----
        const int idx = (blockIdx.x - B_) * 256 + threadIdx.x;   // 0..49151 row-major (j,c)
        const float w = W2[idx];
        const unsigned short hi = f2bf(w);
        const unsigned short lo = f2bf(w - bf2f(hi));
        const int j = idx / D_;
        const int c = idx - j * D_;
        const int l = (c & 15) | (((j >> 3) & 3) << 4);
        const int o = ((c >> 4) * 4 + (j >> 5)) * 512 + l * 8 + (j & 7);
        w2hi[o] = hi;
        w2lo[o] = lo;
        return;
    }

    __shared__ double sred[3][4];
    __shared__ float smean[3];
    __shared__ unsigned long long skey[2][4];
    __shared__ __align__(16) float4 scoord[2][4];

    const int b    = blockIdx.x;
    const int tid  = threadIdx.x;
    const int lane = tid & 63;
    const int wid  = tid >> 6;
    const float* base = xyz + (size_t)b * N_ * 3;

    float lx[FPT], ly[FPT], lz[FPT];
    double sx = 0.0, sy = 0.0, sz = 0.0;
#pragma unroll
    for (int r = 0; r < FPT; ++r) {
        const int i = tid + r * 256;
        lx[r] = base[i * 3 + 0];
        ly[r] = base[i * 3 + 1];
        lz[r] = base[i * 3 + 2];
        sx += lx[r]; sy += ly[r]; sz += lz[r];
    }
#pragma unroll
    for (int off = 32; off >= 1; off >>= 1) {
        sx += __shfl_xor(sx, off);
        sy += __shfl_xor(sy, off);
        sz += __shfl_xor(sz, off);
    }
    if (lane == 0) { sred[0][wid] = sx; sred[1][wid] = sy; sred[2][wid] = sz; }
    __syncthreads();
    if (tid == 0) {
        double tx = 0, ty = 0, tz = 0;
        for (int w = 0; w < 4; ++w) { tx += sred[0][w]; ty += sred[1][w]; tz += sred[2][w]; }
        smean[0] = (float)(tx / (double)N_);
        smean[1] = (float)(ty / (double)N_);
        smean[2] = (float)(tz / (double)N_);
    }
    __syncthreads();
    float cx = smean[0], cy = smean[1], cz = smean[2];

    float dm[FPT];
#pragma unroll
    for (int r = 0; r < FPT; ++r) dm[r] = 1e10f;

    int far;

    // ---- initial round: argmax raw dist-to-mean (parity slot 1) ----
    {
        float vv = -1.0f; int ii = 0;
        float px = lx[0], py = ly[0], pz = lz[0];
#pragma unroll
        for (int r = 0; r < FPT; ++r) {
            const float dx = lx[r] - cx, dy = ly[r] - cy, dz = lz[r] - cz;
            const float d = dx * dx + dy * dy + dz * dz;
            if (d > vv) { vv = d; ii = tid + r * 256; px = lx[r]; py = ly[r]; pz = lz[r]; }
        }
#pragma unroll
        for (int off = 32; off >= 1; off >>= 1) {
            const float ov = __shfl_xor(vv, off);
            const int   oi = __shfl_xor(ii, off);
            if (ov > vv || (ov == vv && oi < ii)) { vv = ov; ii = oi; }
        }
        if (lane == (ii & 63)) {
            skey[1][wid] = ((unsigned long long)__float_as_uint(vv) << 32) | (unsigned)(8191 - ii);
            scoord[1][wid] = make_float4(px, py, pz, 0.0f);
        }
        __syncthreads();
        const unsigned long long k0 = skey[1][0], k1 = skey[1][1], k2 = skey[1][2], k3 = skey[1][3];
        const float4 c0 = scoord[1][0], c1 = scoord[1][1], c2 = scoord[1][2], c3 = scoord[1][3];
        unsigned long long bk = k0; float4 bc = c0;
        if (k1 > bk) { bk = k1; bc = c1; }
        if (k2 > bk) { bk = k2; bc = c2; }
        if (k3 > bk) { bk = k3; bc = c3; }
        far = 8191 - (int)(bk & 0xFFFFFFFFULL);
        cx = bc.x; cy = bc.y; cz = bc.z;
    }

    for (int t = 0; t < G_; ++t) {
        if (tid == 0) {
            cidx[b * G_ + t] = far;
            const size_t o = ((size_t)(b * G_ + t)) * 3;
            centers_out[o + 0] = cx;
            centers_out[o + 1] = cy;
            centers_out[o + 2] = cz;
        }
        if (t == G_ - 1) break;
        const int p = t & 1;

        float vv = -1.0f; int ii = 0;
        float px = lx[0], py = ly[0], pz = lz[0];
#pragma unroll
        for (int r = 0; r < FPT; ++r) {
            const float dx = lx[r] - cx, dy = ly[r] - cy, dz = lz[r] - cz;
            const float d = dx * dx + dy * dy + dz * dz;
            dm[r] = fminf(dm[r], d);
            if (dm[r] > vv) { vv = dm[r]; ii = tid + r * 256; px = lx[r]; py = ly[r]; pz = lz[r]; }
        }
#pragma unroll
        for (int off = 32; off >= 1; off >>= 1) {
            const float ov = __shfl_xor(vv, off);
            const int   oi = __shfl_xor(ii, off);
            if (ov > vv || (ov == vv && oi < ii)) { vv = ov; ii = oi; }
        }
        if (lane == (ii & 63)) {
            skey[p][wid] = ((unsigned long long)__float_as_uint(vv) << 32) | (unsigned)(8191 - ii);
            scoord[p][wid] = make_float4(px, py, pz, 0.0f);
        }
        __syncthreads();
        const unsigned long long k0 = skey[p][0], k1 = skey[p][1], k2 = skey[p][2], k3 = skey[p][3];
        const float4 c0 = scoord[p][0], c1 = scoord[p][1], c2 = scoord[p][2], c3 = scoord[p][3];
        unsigned long long bk = k0; float4 bc = c0;
        if (k1 > bk) { bk = k1; bc = c1; }
        if (k2 > bk) { bk = k2; bc = c2; }
        if (k3 > bk) { bk = k3; bc = c3; }
        far = 8191 - (int)(bk & 0xFFFFFFFFULL);
        cx = bc.x; cy = bc.y; cz = bc.z;
    }
}

// ---------------- Kernel 2: kNN (radix-threshold + rank) + MFMA MLP ----------------
// 512 threads (8 waves) per (b,g) block.  (byte-identical to round 4)

#define NPT 16  // 8192/512

__global__ __launch_bounds__(512) void knn_mlp_kernel(
    const float* __restrict__ xyz,
    const float* __restrict__ W1, const float* __restrict__ b1,
    const float* __restrict__ b2,
    const int* __restrict__ cidx,
    const unsigned short* __restrict__ w2hi,
    const unsigned short* __restrict__ w2lo,
    float* __restrict__ out)
{
    __shared__ unsigned int hist[2048];
    __shared__ unsigned long long ck[CAP_];
    __shared__ __align__(16) unsigned short AHi[4096];
    __shared__ __align__(16) unsigned short ALo[4096];
    __shared__ float sW1[384], sb1[128];
    __shared__ float relx[K_], rely[K_], relz[K_];
    __shared__ int   ssel[K_];
    __shared__ int   scnt, sT;

    const int bg   = blockIdx.x;
    const int b    = bg >> 7;
    const int tid  = threadIdx.x;
    const int lane = tid & 63;
    const int wid  = tid >> 6;
    const float* base = xyz + (size_t)b * N_ * 3;

    const int ci = cidx[bg];
    const float cx = base[ci * 3 + 0];
    const float cy = base[ci * 3 + 1];
    const float cz = base[ci * 3 + 2];

    for (int i = tid; i < 2048; i += 512) hist[i] = 0u;
    if (tid < 384) sW1[tid] = W1[tid];
    else if (tid < 512 && tid >= 384) sb1[tid - 384] = b1[tid - 384];
    if (tid == 0) scnt = 0;

    float d[NPT];
#pragma unroll
    for (int r = 0; r < NPT; ++r) {
        const int i = tid + r * 512;
        const float dx = base[i * 3 + 0] - cx;
        const float dy = base[i * 3 + 1] - cy;
        const float dz = base[i * 3 + 2] - cz;
        d[r] = dx * dx + dy * dy + dz * dz;
    }
    __syncthreads();

#pragma unroll
    for (int r = 0; r < NPT; ++r) atomicAdd(&hist[__float_as_uint(d[r]) >> 21], 1u);
    __syncthreads();

    if (tid < 64) {
        const uint4* h4 = (const uint4*)hist;
        unsigned c = 0;
#pragma unroll
        for (int m = 0; m < 8; ++m) {
            const uint4 v = h4[tid * 8 + m];
            c += v.x + v.y + v.z + v.w;
        }
        unsigned cum = c;
#pragma unroll
        for (int off = 1; off < 64; off <<= 1) {
            const unsigned o = __shfl_up(cum, off);
            if (lane >= off) cum += o;
        }
        const unsigned long long mask = __ballot(cum >= (unsigned)K_);
        const int chunk = __ffsll(mask) - 1;
        const unsigned prior = (chunk > 0) ? (unsigned)__shfl((int)cum, chunk - 1) : 0u;
        const unsigned h2 = hist[chunk * 32 + (lane & 31)];
        unsigned cum2 = h2;
#pragma unroll
        for (int off = 1; off < 32; off <<= 1) {
            const unsigned o = __shfl_up(cum2, off);
            if ((lane & 31) >= off) cum2 += o;
        }
        const unsigned long long mask2 = __ballot(prior + cum2 >= (unsigned)K_) & 0xFFFFFFFFULL;
        const int mbin = __ffsll(mask2) - 1;
        if (lane == 0) sT = chunk * 32 + mbin;
    }
    __syncthreads();

    const unsigned T = (unsigned)sT;
#pragma unroll
    for (int r = 0; r < NPT; ++r) {
        const unsigned bits = __float_as_uint(d[r]);
        if ((bits >> 21) <= T) {
            const int pos = atomicAdd(&scnt, 1);
            if (pos < CAP_) ck[pos] = ((unsigned long long)bits << 32) | (unsigned)(tid + r * 512);
        }
    }
    __syncthreads();

    const int cnt = (scnt < CAP_) ? scnt : CAP_;
    for (int c = tid; c < cnt; c += 512) {
        const unsigned long long kc = ck[c];
        int rk = 0;
        for (int j = 0; j < cnt; ++j) rk += (ck[j] < kc) ? 1 : 0;
        if (rk < K_) ssel[rk] = (int)(kc & 0xFFFFFFFFULL);
    }
    __syncthreads();

    if (tid < K_) {
        const int si = ssel[tid];
        out[GIDX_OFF + (size_t)bg * K_ + tid] = (float)si;
        relx[tid] = base[si * 3 + 0] - cx;
        rely[tid] = base[si * 3 + 1] - cy;
        relz[tid] = base[si * 3 + 2] - cz;
    }
    __syncthreads();

    // ---- h = gelu(rel@W1+b1), computed directly in A-fragment layout ----
    {
        const int p  = wid;
        const int row = ((p >> 2) << 4) + (lane & 15);
        const int j0 = ((p & 3) << 5) + (((lane >> 4) & 3) << 3);
        const float rx = relx[row], ry = rely[row], rz = relz[row];
        bf16x8 hv, lv;
#pragma unroll
        for (int e = 0; e < 8; ++e) {
            const int j = j0 + e;
            const float t = fmaf(rx, sW1[j], fmaf(ry, sW1[128 + j], fmaf(rz, sW1[256 + j], sb1[j])));
            const float g = 0.5f * t * (1.0f + erff(t * 0.70710678118654752f));
            const unsigned short hi = f2bf(g);
            hv[e] = (short)hi;
            lv[e] = (short)f2bf(g - bf2f(hi));
        }
        *(bf16x8*)&AHi[p * 512 + lane * 8] = hv;
        *(bf16x8*)&ALo[p * 512 + lane * 8] = lv;
    }
    __syncthreads();

    // ---- MFMA GEMM: wave w owns N-tiles {3w, 3w+1, 3w+2} ----
    bf16x8 ah[8], al[8];
#pragma unroll
    for (int p = 0; p < 8; ++p) {
        ah[p] = *(const bf16x8*)&AHi[p * 512 + lane * 8];
        al[p] = *(const bf16x8*)&ALo[p * 512 + lane * 8];
    }

#pragma unroll
    for (int nn = 0; nn < 3; ++nn) {
        const int n = wid * 3 + nn;
        f32x4 acc0 = {0.f, 0.f, 0.f, 0.f};
        f32x4 acc1 = {0.f, 0.f, 0.f, 0.f};
#pragma unroll
        for (int kb = 0; kb < 4; ++kb) {
            const int off = (n * 4 + kb) * 512 + lane * 8;
            const bf16x8 bh = *(const bf16x8*)&w2hi[off];
            const bf16x8 bl = *(const bf16x8*)&w2lo[off];
            acc0 = __builtin_amdgcn_mfma_f32_16x16x32_bf16(ah[kb], bh, acc0, 0, 0, 0);
            acc0 = __builtin_amdgcn_mfma_f32_16x16x32_bf16(ah[kb], bl, acc0, 0, 0, 0);
            acc0 = __builtin_amdgcn_mfma_f32_16x16x32_bf16(al[kb], bh, acc0, 0, 0, 0);
            acc1 = __builtin_amdgcn_mfma_f32_16x16x32_bf16(ah[4 + kb], bh, acc1, 0, 0, 0);
            acc1 = __builtin_amdgcn_mfma_f32_16x16x32_bf16(ah[4 + kb], bl, acc1, 0, 0, 0);
            acc1 = __builtin_amdgcn_mfma_f32_16x16x32_bf16(al[4 + kb], bh, acc1, 0, 0, 0);
        }
        float cm = fmaxf(fmaxf(fmaxf(acc0[0], acc0[1]), fmaxf(acc0[2], acc0[3])),
                         fmaxf(fmaxf(acc1[0], acc1[1]), fmaxf(acc1[2], acc1[3])));
        cm = fmaxf(cm, __shfl_xor(cm, 16));
        cm = fmaxf(cm, __shfl_xor(cm, 32));
        if (lane < 16) {
            const int col = n * 16 + lane;
            out[(size_t)bg * D_ + col] = cm + b2[col];
        }
    }
}

// ---------------- launch ----------------

extern "C" void kernel_launch(void* const* d_in, const int* in_sizes, int n_in,
                              void* d_out, int out_size, void* d_ws, size_t ws_size,
                              hipStream_t stream) {
    const float* xyz = (const float*)d_in[0];
    const float* W1  = (const float*)d_in[1];
    const float* b1  = (const float*)d_in[2];
    const float* W2  = (const float*)d_in[3];
    const float* b2  = (const float*)d_in[4];
    float* out = (float*)d_out;

    char* ws = (char*)d_ws;
    int* cidx = (int*)ws;                                        // 16384 B
    unsigned short* w2hi = (unsigned short*)(ws + 16384);        // 98304 B
    unsigned short* w2lo = (unsigned short*)(ws + 16384 + 98304);// 98304 B

    // blocks 0..31: FPS (256 thr); blocks 32..223: W2 fragment prep (49152 / 256)
    fps_prep_kernel<<<dim3(B_ + 192), dim3(256), 0, stream>>>(xyz, W2, out + CEN_OFF, cidx, w2hi, w2lo);
    knn_mlp_kernel<<<dim3(B_ * G_), dim3(512), 0, stream>>>(xyz, W1, b1, b2, cidx, w2hi, w2lo, out);
}